// Round 1
// 312.140 us; speedup vs baseline: 1.0066x; 1.0066x over previous
//
#include <hip/hip_runtime.h>
#include <hip/hip_fp16.h>

// GCN 2-layer: 256 -> 16 -> 1, N=100000, E=3.2M + self loops.
// R8: two-level radix. k_p1 bins edges by super-bucket (256 nodes, dst>>8);
// k_sortsb counting-sorts each super-bucket entirely in LDS (8-bit local key),
// emitting fully dst-sorted src lists + rowp + isq in one pass.
//   out[d] = isq[d]*(sum_src ts[src] + ts[d]) + b2,  ts = (h2 @ W2)*isq
//   h2 = relu(isq[d]*(sum_src hs[src] + hs[d]) + b1), hs = (x @ W1)*isq
// Edge pack in pass1: (src<<8)|(dst&255), sb = dst>>8 (src<2^17 -> 25 bits).
// R9: k_lin1 rewritten — 1 thread/node, all 16 features; W1 read via
// wave-uniform indices -> compiler emits s_load (SGPR broadcast), removing
// the LDS stage entirely (old version: 4x ds_read_b128 per 16 FMAs was
// ~31us of LDS-pipe issue out of 59us).

#define SBSH 8              // 256 nodes per super-bucket
#define SBCAP 10240         // capacity (mean 8168, sigma ~90 -> +23 sigma)
#define HPAD 400            // >= Bsb = ceil(N/256) = 391
#define BINTHREADS 1024
#define ITEMS 32            // edges per thread in k_p1

__global__ void k_init(int* __restrict__ gcur, int Bsb) {
    int i = blockIdx.x * blockDim.x + threadIdx.x;
    if (i < Bsb) gcur[i] = i * SBCAP;
}

// Pass 1: counting scatter into super-bucket regions. Per-block LDS histogram,
// one bulk global claim per super-bucket, ~84-int runs (amp ~1.2).
__global__ __launch_bounds__(BINTHREADS) void k_p1(
    const int* __restrict__ src, const int* __restrict__ dst,
    int* __restrict__ gcur, int* __restrict__ pairs, int E, int Bsb)
{
    __shared__ int hist[HPAD];
    const int t = threadIdx.x;
    const int base4 = blockIdx.x * (BINTHREADS * ITEMS / 4);
    for (int i = t; i < HPAD; i += BINTHREADS) hist[i] = 0;
    __syncthreads();

    int4 dd[ITEMS / 4];
    #pragma unroll
    for (int r = 0; r < ITEMS / 4; ++r) {
        const int i4 = base4 + r * BINTHREADS + t;
        const int i = i4 << 2;
        int4 v;
        if (i + 3 < E) v = ((const int4*)dst)[i4];
        else {
            v.x = (i     < E) ? dst[i]     : -1;
            v.y = (i + 1 < E) ? dst[i + 1] : -1;
            v.z = (i + 2 < E) ? dst[i + 2] : -1;
            v.w = (i + 3 < E) ? dst[i + 3] : -1;
        }
        dd[r] = v;
        if (v.x >= 0) atomicAdd(&hist[v.x >> SBSH], 1);
        if (v.y >= 0) atomicAdd(&hist[v.y >> SBSH], 1);
        if (v.z >= 0) atomicAdd(&hist[v.z >> SBSH], 1);
        if (v.w >= 0) atomicAdd(&hist[v.w >> SBSH], 1);
    }
    __syncthreads();
    for (int i = t; i < Bsb; i += BINTHREADS) {
        int c = hist[i];
        hist[i] = c ? atomicAdd(&gcur[i], c) : 0;   // bulk claim -> abs base
    }
    __syncthreads();
    #pragma unroll
    for (int r = 0; r < ITEMS / 4; ++r) {
        const int i4 = base4 + r * BINTHREADS + t;
        const int i = i4 << 2;
        int4 s;
        if (i + 3 < E) s = ((const int4*)src)[i4];
        else {
            s.x = (i     < E) ? src[i]     : 0;
            s.y = (i + 1 < E) ? src[i + 1] : 0;
            s.z = (i + 2 < E) ? src[i + 2] : 0;
            s.w = (i + 3 < E) ? src[i + 3] : 0;
        }
        int4 v = dd[r];
        if (v.x >= 0) { int p = atomicAdd(&hist[v.x >> SBSH], 1); pairs[p] = (s.x << SBSH) | (v.x & 255); }
        if (v.y >= 0) { int p = atomicAdd(&hist[v.y >> SBSH], 1); pairs[p] = (s.y << SBSH) | (v.y & 255); }
        if (v.z >= 0) { int p = atomicAdd(&hist[v.z >> SBSH], 1); pairs[p] = (s.z << SBSH) | (v.z & 255); }
        if (v.w >= 0) { int p = atomicAdd(&hist[v.w >> SBSH], 1); pairs[p] = (s.w << SBSH) | (v.w & 255); }
    }
}

// Pass 2: per-super-bucket counting sort by 8-bit local dst, fully in LDS.
// Emits: pairs region <- src sorted by dst-local (coalesced write-back);
// rowp[sb*257 + l] = exclusive run offsets (257 entries); isq.
__global__ __launch_bounds__(1024) void k_sortsb(
    int* __restrict__ pairs, const int* __restrict__ gcur,
    int* __restrict__ rowp, float* __restrict__ isq, int N)
{
    __shared__ int e[SBCAP];             // 40KB staged edges
    __shared__ int hist[256];
    __shared__ int cur[256];
    __shared__ int wsum[4];
    const int t = threadIdx.x, sb = blockIdx.x;
    const int beg = sb * SBCAP;
    const int cnt = gcur[sb] - beg;
    if (t < 256) hist[t] = 0;
    __syncthreads();
    for (int i = t; i < cnt; i += 1024) {
        int p = pairs[beg + i];
        e[i] = p;
        atomicAdd(&hist[p & 255], 1);
    }
    __syncthreads();
    int c = 0, v = 0;
    if (t < 256) {                       // 4-wave scan of 256 counts
        const int lane = t & 63, w = t >> 6;
        c = hist[t];
        v = c;
        #pragma unroll
        for (int off = 1; off < 64; off <<= 1) {
            int u = __shfl_up(v, off, 64);
            if (lane >= off) v += u;
        }
        if (lane == 63) wsum[w] = v;
    }
    __syncthreads();
    if (t < 256) {
        const int w = t >> 6;
        int add = 0;
        #pragma unroll
        for (int i = 0; i < 3; ++i) if (i < w) add += wsum[i];
        int inc = v + add;               // inclusive prefix
        int exc = inc - c;
        cur[t] = exc;
        rowp[sb * 257 + t] = exc;
        if (t == 255) rowp[sb * 257 + 256] = inc;   // == cnt
        int n = (sb << SBSH) + t;
        if (n < N) isq[n] = rsqrtf((float)(c + 1)); // +1 self loop
    }
    __syncthreads();
    for (int i = t; i < cnt; i += 1024) {
        int p = e[i];
        int pos = atomicAdd(&cur[p & 255], 1);
        pairs[beg + pos] = p >> SBSH;    // sorted src
    }
}

// hs16[n][f] = half( dot(x[n,:], W1[:,f]) * isq[n] ).
// R9: one thread per node, 16 accumulators. W1 addresses are wave-uniform
// (loop-counter-derived only) -> s_load into SGPRs; zero LDS, one
// global_load_dwordx4 of x per 4 k-values. v_fma_f32 takes one SGPR operand.
__global__ __launch_bounds__(256) void k_lin1(
    const float* __restrict__ x, const float* __restrict__ W1,
    const float* __restrict__ isq, __half* __restrict__ hs16, int N)
{
    const int n = blockIdx.x * 256 + threadIdx.x;
    if (n >= N) return;
    const float4* xr = (const float4*)(x + ((size_t)n << 8));
    float acc[16];
    #pragma unroll
    for (int f = 0; f < 16; ++f) acc[f] = 0.f;
    #pragma unroll 2
    for (int k4 = 0; k4 < 64; ++k4) {
        const float4 xa = xr[k4];
        const float4* wr = (const float4*)(W1 + (k4 << 6));  // k=4*k4.., 16 f each
        const float xv[4] = { xa.x, xa.y, xa.z, xa.w };
        #pragma unroll
        for (int j = 0; j < 4; ++j) {
            #pragma unroll
            for (int f4 = 0; f4 < 4; ++f4) {
                const float4 w = wr[(j << 2) + f4];   // uniform -> s_load
                acc[(f4 << 2) + 0] = fmaf(xv[j], w.x, acc[(f4 << 2) + 0]);
                acc[(f4 << 2) + 1] = fmaf(xv[j], w.y, acc[(f4 << 2) + 1]);
                acc[(f4 << 2) + 2] = fmaf(xv[j], w.z, acc[(f4 << 2) + 2]);
                acc[(f4 << 2) + 3] = fmaf(xv[j], w.w, acc[(f4 << 2) + 3]);
            }
        }
    }
    const float iq = isq[n];
    __half2* o = (__half2*)&hs16[(size_t)n << 4];
    #pragma unroll
    for (int f2 = 0; f2 < 8; ++f2)
        o[f2] = __floats2half2_rn(acc[2 * f2] * iq, acc[2 * f2 + 1] * iq);
}

// Layer-1 aggregation: 4 lanes per node (4 features each, 8B loads), run-scan
// with register accumulation, fused relu/W2/isq epilogue. No atomics.
// Block = 64-node group g; sb = g>>2, local base = (g&3)*64.
__global__ __launch_bounds__(256) void k_agg1(
    const int* __restrict__ sorted, const int* __restrict__ rowp,
    const __half* __restrict__ hs16, const float* __restrict__ isq,
    const float* __restrict__ b1, const float* __restrict__ W2,
    float* __restrict__ ts, int N)
{
    const int t = threadIdx.x, g = blockIdx.x;
    const int l = t >> 2, q = t & 3;
    const int n = g * 64 + l;
    if (n >= N) return;
    const int sb = n >> SBSH, L = n & 255;
    const int rbeg = sb * SBCAP + rowp[sb * 257 + L];
    const int rend = sb * SBCAP + rowp[sb * 257 + L + 1];
    const float2* h2 = (const float2*)hs16;
    float a0 = 0.f, a1 = 0.f, a2 = 0.f, a3 = 0.f;
    int j = rbeg;
    for (; j + 2 <= rend; j += 2) {
        int s0 = sorted[j], s1 = sorted[j + 1];
        float2 ra = h2[s0 * 4 + q];
        float2 rb = h2[s1 * 4 + q];
        union { float f; __half2 h; } ca0, ca1, cb0, cb1;
        ca0.f = ra.x; ca1.f = ra.y; cb0.f = rb.x; cb1.f = rb.y;
        float2 fa0 = __half22float2(ca0.h), fa1 = __half22float2(ca1.h);
        float2 fb0 = __half22float2(cb0.h), fb1 = __half22float2(cb1.h);
        a0 += fa0.x + fb0.x; a1 += fa0.y + fb0.y;
        a2 += fa1.x + fb1.x; a3 += fa1.y + fb1.y;
    }
    if (j < rend) {
        int s0 = sorted[j];
        float2 ra = h2[s0 * 4 + q];
        union { float f; __half2 h; } ca0, ca1;
        ca0.f = ra.x; ca1.f = ra.y;
        float2 fa0 = __half22float2(ca0.h), fa1 = __half22float2(ca1.h);
        a0 += fa0.x; a1 += fa0.y; a2 += fa1.x; a3 += fa1.y;
    }
    {   // self loop
        float2 rs = h2[(size_t)n * 4 + q];
        union { float f; __half2 h; } c0, c1;
        c0.f = rs.x; c1.f = rs.y;
        float2 f0 = __half22float2(c0.h), f1 = __half22float2(c1.h);
        a0 += f0.x; a1 += f0.y; a2 += f1.x; a3 += f1.y;
    }
    const float iq = isq[n];
    const int f0i = q * 4;
    float p = fmaxf(a0 * iq + b1[f0i + 0], 0.f) * W2[f0i + 0]
            + fmaxf(a1 * iq + b1[f0i + 1], 0.f) * W2[f0i + 1]
            + fmaxf(a2 * iq + b1[f0i + 2], 0.f) * W2[f0i + 2]
            + fmaxf(a3 * iq + b1[f0i + 3], 0.f) * W2[f0i + 3];
    p += __shfl_xor(p, 1, 4);
    p += __shfl_xor(p, 2, 4);
    if (q == 0) ts[n] = p * iq;
}

// Layer-2: 1 thread per node, run-scan over sorted srcs, scalar ts gather.
__global__ __launch_bounds__(256) void k_agg2(
    const int* __restrict__ sorted, const int* __restrict__ rowp,
    const float* __restrict__ ts, const float* __restrict__ isq,
    const float* __restrict__ b2, float* __restrict__ out, int N)
{
    const int n = blockIdx.x * 256 + threadIdx.x;
    if (n >= N) return;
    const int sb = n >> SBSH, L = n & 255;
    const int rbeg = sb * SBCAP + rowp[sb * 257 + L];
    const int rend = sb * SBCAP + rowp[sb * 257 + L + 1];
    float acc = ts[n];                   // self loop
    int j = rbeg;
    for (; j + 4 <= rend; j += 4) {
        int s0 = sorted[j], s1 = sorted[j + 1], s2 = sorted[j + 2], s3 = sorted[j + 3];
        acc += (ts[s0] + ts[s1]) + (ts[s2] + ts[s3]);
    }
    for (; j < rend; ++j) acc += ts[sorted[j]];
    out[n] = acc * isq[n] + b2[0];
}

extern "C" void kernel_launch(void* const* d_in, const int* in_sizes, int n_in,
                              void* d_out, int out_size, void* d_ws, size_t ws_size,
                              hipStream_t stream) {
    const float* x  = (const float*)d_in[0];
    const int*   ei = (const int*)d_in[1];
    const float* W1 = (const float*)d_in[2];
    const float* b1 = (const float*)d_in[3];
    const float* W2 = (const float*)d_in[4];
    const float* b2 = (const float*)d_in[5];
    const int N = in_sizes[0] / 256;
    const int E = in_sizes[1] / 2;
    const int* src = ei;
    const int* dst = ei + E;
    const int Bsb = (N + 255) >> SBSH;   // 391

    char* w = (char*)d_ws;
    float*  isq   = (float*)w;  w += (size_t)N * 4;
    int*    gcur  = (int*)w;    w += HPAD * 4;
    int*    pairs = (int*)w;    w += (size_t)Bsb * SBCAP * 4;   // 16.0 MB
    int*    rowp  = (int*)w;    w += (size_t)Bsb * 257 * 4;     // 402 KB
    __half* hs16  = (__half*)w; w += (size_t)N * 32;            // 3.2 MB
    float*  ts    = (float*)w;  w += (size_t)N * 4;
    float*  out   = (float*)d_out;

    k_init<<<(Bsb + 255) / 256, 256, 0, stream>>>(gcur, Bsb);

    const int nbBin = (E + BINTHREADS * ITEMS - 1) / (BINTHREADS * ITEMS);  // 98
    k_p1<<<nbBin, BINTHREADS, 0, stream>>>(src, dst, gcur, pairs, E, Bsb);

    k_sortsb<<<Bsb, 1024, 0, stream>>>(pairs, gcur, rowp, isq, N);

    k_lin1<<<(N + 255) / 256, 256, 0, stream>>>(x, W1, isq, hs16, N);

    k_agg1<<<(N + 63) / 64, 256, 0, stream>>>(pairs, rowp, hs16, isq, b1, W2, ts, N);
    k_agg2<<<(N + 255) / 256, 256, 0, stream>>>(pairs, rowp, ts, isq, b2, out, N);
}

// Round 2
// 300.388 us; speedup vs baseline: 1.0459x; 1.0391x over previous
//
#include <hip/hip_runtime.h>
#include <hip/hip_fp16.h>

// GCN 2-layer: 256 -> 16 -> 1, N=100000, E=3.2M + self loops.
// R8: two-level radix. k_p1 bins edges by super-bucket (256 nodes, dst>>8);
// k_sortsb counting-sorts each super-bucket entirely in LDS (8-bit local key),
// emitting fully dst-sorted src lists + rowp + isq in one pass.
//   out[d] = isq[d]*(sum_src ts[src] + ts[d]) + b2,  ts = (h2 @ W2)*isq
//   h2 = relu(isq[d]*(sum_src hs[src] + hs[d]) + b1), hs = (x @ W1)*isq
// Edge pack in pass1: (src<<8)|(dst&255), sb = dst>>8 (src<2^17 -> 25 bits).
// R9: k_lin1 -> 1 thread/node, wave-uniform W1 (s_load), no LDS.
// R10: (a) k_p1 ITEMS 32->8: grid 98->391 blocks — old grid left 158/256 CUs
//      idle (wall = one block's serial scatter). (b) k_lin1 batches x-loads
//      8-wide before use: old unroll-2 had ~12KB/CU in flight vs ~9.2KB
//      latency-BW product (zero slack -> latency-bound at ~55us).

#define SBSH 8              // 256 nodes per super-bucket
#define SBCAP 10240         // capacity (mean 8168, sigma ~90 -> +23 sigma)
#define HPAD 400            // >= Bsb = ceil(N/256) = 391
#define BINTHREADS 1024
#define ITEMS 8             // edges per thread in k_p1 (R10: was 32)

__global__ void k_init(int* __restrict__ gcur, int Bsb) {
    int i = blockIdx.x * blockDim.x + threadIdx.x;
    if (i < Bsb) gcur[i] = i * SBCAP;
}

// Pass 1: counting scatter into super-bucket regions. Per-block LDS histogram,
// one bulk global claim per super-bucket (~21-int runs at ITEMS=8, amp ~1.4).
__global__ __launch_bounds__(BINTHREADS) void k_p1(
    const int* __restrict__ src, const int* __restrict__ dst,
    int* __restrict__ gcur, int* __restrict__ pairs, int E, int Bsb)
{
    __shared__ int hist[HPAD];
    const int t = threadIdx.x;
    const int base4 = blockIdx.x * (BINTHREADS * ITEMS / 4);
    for (int i = t; i < HPAD; i += BINTHREADS) hist[i] = 0;
    __syncthreads();

    int4 dd[ITEMS / 4];
    #pragma unroll
    for (int r = 0; r < ITEMS / 4; ++r) {
        const int i4 = base4 + r * BINTHREADS + t;
        const int i = i4 << 2;
        int4 v;
        if (i + 3 < E) v = ((const int4*)dst)[i4];
        else {
            v.x = (i     < E) ? dst[i]     : -1;
            v.y = (i + 1 < E) ? dst[i + 1] : -1;
            v.z = (i + 2 < E) ? dst[i + 2] : -1;
            v.w = (i + 3 < E) ? dst[i + 3] : -1;
        }
        dd[r] = v;
        if (v.x >= 0) atomicAdd(&hist[v.x >> SBSH], 1);
        if (v.y >= 0) atomicAdd(&hist[v.y >> SBSH], 1);
        if (v.z >= 0) atomicAdd(&hist[v.z >> SBSH], 1);
        if (v.w >= 0) atomicAdd(&hist[v.w >> SBSH], 1);
    }
    __syncthreads();
    for (int i = t; i < Bsb; i += BINTHREADS) {
        int c = hist[i];
        hist[i] = c ? atomicAdd(&gcur[i], c) : 0;   // bulk claim -> abs base
    }
    __syncthreads();
    #pragma unroll
    for (int r = 0; r < ITEMS / 4; ++r) {
        const int i4 = base4 + r * BINTHREADS + t;
        const int i = i4 << 2;
        int4 s;
        if (i + 3 < E) s = ((const int4*)src)[i4];
        else {
            s.x = (i     < E) ? src[i]     : 0;
            s.y = (i + 1 < E) ? src[i + 1] : 0;
            s.z = (i + 2 < E) ? src[i + 2] : 0;
            s.w = (i + 3 < E) ? src[i + 3] : 0;
        }
        int4 v = dd[r];
        if (v.x >= 0) { int p = atomicAdd(&hist[v.x >> SBSH], 1); pairs[p] = (s.x << SBSH) | (v.x & 255); }
        if (v.y >= 0) { int p = atomicAdd(&hist[v.y >> SBSH], 1); pairs[p] = (s.y << SBSH) | (v.y & 255); }
        if (v.z >= 0) { int p = atomicAdd(&hist[v.z >> SBSH], 1); pairs[p] = (s.z << SBSH) | (v.z & 255); }
        if (v.w >= 0) { int p = atomicAdd(&hist[v.w >> SBSH], 1); pairs[p] = (s.w << SBSH) | (v.w & 255); }
    }
}

// Pass 2: per-super-bucket counting sort by 8-bit local dst, fully in LDS.
// Emits: pairs region <- src sorted by dst-local (coalesced write-back);
// rowp[sb*257 + l] = exclusive run offsets (257 entries); isq.
__global__ __launch_bounds__(1024) void k_sortsb(
    int* __restrict__ pairs, const int* __restrict__ gcur,
    int* __restrict__ rowp, float* __restrict__ isq, int N)
{
    __shared__ int e[SBCAP];             // 40KB staged edges
    __shared__ int hist[256];
    __shared__ int cur[256];
    __shared__ int wsum[4];
    const int t = threadIdx.x, sb = blockIdx.x;
    const int beg = sb * SBCAP;
    const int cnt = gcur[sb] - beg;
    if (t < 256) hist[t] = 0;
    __syncthreads();
    for (int i = t; i < cnt; i += 1024) {
        int p = pairs[beg + i];
        e[i] = p;
        atomicAdd(&hist[p & 255], 1);
    }
    __syncthreads();
    int c = 0, v = 0;
    if (t < 256) {                       // 4-wave scan of 256 counts
        const int lane = t & 63, w = t >> 6;
        c = hist[t];
        v = c;
        #pragma unroll
        for (int off = 1; off < 64; off <<= 1) {
            int u = __shfl_up(v, off, 64);
            if (lane >= off) v += u;
        }
        if (lane == 63) wsum[w] = v;
    }
    __syncthreads();
    if (t < 256) {
        const int w = t >> 6;
        int add = 0;
        #pragma unroll
        for (int i = 0; i < 3; ++i) if (i < w) add += wsum[i];
        int inc = v + add;               // inclusive prefix
        int exc = inc - c;
        cur[t] = exc;
        rowp[sb * 257 + t] = exc;
        if (t == 255) rowp[sb * 257 + 256] = inc;   // == cnt
        int n = (sb << SBSH) + t;
        if (n < N) isq[n] = rsqrtf((float)(c + 1)); // +1 self loop
    }
    __syncthreads();
    for (int i = t; i < cnt; i += 1024) {
        int p = e[i];
        int pos = atomicAdd(&cur[p & 255], 1);
        pairs[beg + pos] = p >> SBSH;    // sorted src
    }
}

// hs16[n][f] = half( dot(x[n,:], W1[:,f]) * isq[n] ).
// R10: one thread per node, 16 accumulators; x loaded in explicit 8-wide
// float4 batches (>=8 loads in flight -> ~50KB/CU, 5x latency-BW product).
// W1 addresses are wave-uniform -> s_load into SGPRs; zero LDS.
__global__ __launch_bounds__(256) void k_lin1(
    const float* __restrict__ x, const float* __restrict__ W1,
    const float* __restrict__ isq, __half* __restrict__ hs16, int N)
{
    const int n = blockIdx.x * 256 + threadIdx.x;
    if (n >= N) return;
    const float4* xr = (const float4*)(x + ((size_t)n << 8));
    float acc[16];
    #pragma unroll
    for (int f = 0; f < 16; ++f) acc[f] = 0.f;
    #pragma unroll 2
    for (int kb = 0; kb < 8; ++kb) {
        float4 xa[8];
        #pragma unroll
        for (int u = 0; u < 8; ++u) xa[u] = xr[(kb << 3) + u];   // 8 loads in flight
        #pragma unroll
        for (int u = 0; u < 8; ++u) {
            const int k4 = (kb << 3) + u;
            const float4* wr = (const float4*)(W1 + (k4 << 6));  // uniform -> s_load
            const float xv[4] = { xa[u].x, xa[u].y, xa[u].z, xa[u].w };
            #pragma unroll
            for (int j = 0; j < 4; ++j) {
                #pragma unroll
                for (int f4 = 0; f4 < 4; ++f4) {
                    const float4 w = wr[(j << 2) + f4];
                    acc[(f4 << 2) + 0] = fmaf(xv[j], w.x, acc[(f4 << 2) + 0]);
                    acc[(f4 << 2) + 1] = fmaf(xv[j], w.y, acc[(f4 << 2) + 1]);
                    acc[(f4 << 2) + 2] = fmaf(xv[j], w.z, acc[(f4 << 2) + 2]);
                    acc[(f4 << 2) + 3] = fmaf(xv[j], w.w, acc[(f4 << 2) + 3]);
                }
            }
        }
    }
    const float iq = isq[n];
    __half2* o = (__half2*)&hs16[(size_t)n << 4];
    #pragma unroll
    for (int f2 = 0; f2 < 8; ++f2)
        o[f2] = __floats2half2_rn(acc[2 * f2] * iq, acc[2 * f2 + 1] * iq);
}

// Layer-1 aggregation: 4 lanes per node (4 features each, 8B loads), run-scan
// with register accumulation, fused relu/W2/isq epilogue. No atomics.
__global__ __launch_bounds__(256) void k_agg1(
    const int* __restrict__ sorted, const int* __restrict__ rowp,
    const __half* __restrict__ hs16, const float* __restrict__ isq,
    const float* __restrict__ b1, const float* __restrict__ W2,
    float* __restrict__ ts, int N)
{
    const int t = threadIdx.x, g = blockIdx.x;
    const int l = t >> 2, q = t & 3;
    const int n = g * 64 + l;
    if (n >= N) return;
    const int sb = n >> SBSH, L = n & 255;
    const int rbeg = sb * SBCAP + rowp[sb * 257 + L];
    const int rend = sb * SBCAP + rowp[sb * 257 + L + 1];
    const float2* h2 = (const float2*)hs16;
    float a0 = 0.f, a1 = 0.f, a2 = 0.f, a3 = 0.f;
    int j = rbeg;
    for (; j + 2 <= rend; j += 2) {
        int s0 = sorted[j], s1 = sorted[j + 1];
        float2 ra = h2[s0 * 4 + q];
        float2 rb = h2[s1 * 4 + q];
        union { float f; __half2 h; } ca0, ca1, cb0, cb1;
        ca0.f = ra.x; ca1.f = ra.y; cb0.f = rb.x; cb1.f = rb.y;
        float2 fa0 = __half22float2(ca0.h), fa1 = __half22float2(ca1.h);
        float2 fb0 = __half22float2(cb0.h), fb1 = __half22float2(cb1.h);
        a0 += fa0.x + fb0.x; a1 += fa0.y + fb0.y;
        a2 += fa1.x + fb1.x; a3 += fa1.y + fb1.y;
    }
    if (j < rend) {
        int s0 = sorted[j];
        float2 ra = h2[s0 * 4 + q];
        union { float f; __half2 h; } ca0, ca1;
        ca0.f = ra.x; ca1.f = ra.y;
        float2 fa0 = __half22float2(ca0.h), fa1 = __half22float2(ca1.h);
        a0 += fa0.x; a1 += fa0.y; a2 += fa1.x; a3 += fa1.y;
    }
    {   // self loop
        float2 rs = h2[(size_t)n * 4 + q];
        union { float f; __half2 h; } c0, c1;
        c0.f = rs.x; c1.f = rs.y;
        float2 f0 = __half22float2(c0.h), f1 = __half22float2(c1.h);
        a0 += f0.x; a1 += f0.y; a2 += f1.x; a3 += f1.y;
    }
    const float iq = isq[n];
    const int f0i = q * 4;
    float p = fmaxf(a0 * iq + b1[f0i + 0], 0.f) * W2[f0i + 0]
            + fmaxf(a1 * iq + b1[f0i + 1], 0.f) * W2[f0i + 1]
            + fmaxf(a2 * iq + b1[f0i + 2], 0.f) * W2[f0i + 2]
            + fmaxf(a3 * iq + b1[f0i + 3], 0.f) * W2[f0i + 3];
    p += __shfl_xor(p, 1, 4);
    p += __shfl_xor(p, 2, 4);
    if (q == 0) ts[n] = p * iq;
}

// Layer-2: 1 thread per node, run-scan over sorted srcs, scalar ts gather.
__global__ __launch_bounds__(256) void k_agg2(
    const int* __restrict__ sorted, const int* __restrict__ rowp,
    const float* __restrict__ ts, const float* __restrict__ isq,
    const float* __restrict__ b2, float* __restrict__ out, int N)
{
    const int n = blockIdx.x * 256 + threadIdx.x;
    if (n >= N) return;
    const int sb = n >> SBSH, L = n & 255;
    const int rbeg = sb * SBCAP + rowp[sb * 257 + L];
    const int rend = sb * SBCAP + rowp[sb * 257 + L + 1];
    float acc = ts[n];                   // self loop
    int j = rbeg;
    for (; j + 4 <= rend; j += 4) {
        int s0 = sorted[j], s1 = sorted[j + 1], s2 = sorted[j + 2], s3 = sorted[j + 3];
        acc += (ts[s0] + ts[s1]) + (ts[s2] + ts[s3]);
    }
    for (; j < rend; ++j) acc += ts[sorted[j]];
    out[n] = acc * isq[n] + b2[0];
}

extern "C" void kernel_launch(void* const* d_in, const int* in_sizes, int n_in,
                              void* d_out, int out_size, void* d_ws, size_t ws_size,
                              hipStream_t stream) {
    const float* x  = (const float*)d_in[0];
    const int*   ei = (const int*)d_in[1];
    const float* W1 = (const float*)d_in[2];
    const float* b1 = (const float*)d_in[3];
    const float* W2 = (const float*)d_in[4];
    const float* b2 = (const float*)d_in[5];
    const int N = in_sizes[0] / 256;
    const int E = in_sizes[1] / 2;
    const int* src = ei;
    const int* dst = ei + E;
    const int Bsb = (N + 255) >> SBSH;   // 391

    char* w = (char*)d_ws;
    float*  isq   = (float*)w;  w += (size_t)N * 4;
    int*    gcur  = (int*)w;    w += HPAD * 4;
    int*    pairs = (int*)w;    w += (size_t)Bsb * SBCAP * 4;   // 16.0 MB
    int*    rowp  = (int*)w;    w += (size_t)Bsb * 257 * 4;     // 402 KB
    __half* hs16  = (__half*)w; w += (size_t)N * 32;            // 3.2 MB
    float*  ts    = (float*)w;  w += (size_t)N * 4;
    float*  out   = (float*)d_out;

    k_init<<<(Bsb + 255) / 256, 256, 0, stream>>>(gcur, Bsb);

    const int nbBin = (E + BINTHREADS * ITEMS - 1) / (BINTHREADS * ITEMS);  // 391
    k_p1<<<nbBin, BINTHREADS, 0, stream>>>(src, dst, gcur, pairs, E, Bsb);

    k_sortsb<<<Bsb, 1024, 0, stream>>>(pairs, gcur, rowp, isq, N);

    k_lin1<<<(N + 255) / 256, 256, 0, stream>>>(x, W1, isq, hs16, N);

    k_agg1<<<(N + 63) / 64, 256, 0, stream>>>(pairs, rowp, hs16, isq, b1, W2, ts, N);
    k_agg2<<<(N + 255) / 256, 256, 0, stream>>>(pairs, rowp, ts, isq, b2, out, N);
}

// Round 3
// 280.595 us; speedup vs baseline: 1.1197x; 1.0705x over previous
//
#include <hip/hip_runtime.h>
#include <hip/hip_fp16.h>

// GCN 2-layer: 256 -> 16 -> 1, N=100000, E=3.2M + self loops.
// R8: two-level radix. k_p1 bins edges by super-bucket (256 nodes, dst>>8);
// k_sortsb counting-sorts each super-bucket (8-bit local key) -> dst-sorted
// src lists + rowp + isq.
//   out[d] = isq[d]*(sum_src ts[src] + ts[d]) + b2,  ts = (h2 @ W2)*isq
//   h2 = relu(isq[d]*(sum_src hs[src] + hs[d]) + b1), hs = (x @ W1)*isq
// R10: k_p1 ITEMS 8 (391 blocks).
// R11: (a) k_lin1 2-way K-split by WAVE (grid 782, 3 waves/SIMD vs 1.5;
//      readfirstlane keeps W1 index wave-uniform -> s_load); LDS combine.
//      (b) k_agg2 4 lanes/node (grid 1563, coalesced sorted reads).
//      (c) k_sortsb scatters in LDS, write-back fully coalesced int4
//      (was 12.8M scattered 4B global stores = per-line L2 requests).

#define SBSH 8              // 256 nodes per super-bucket
#define SBCAP 10240         // global region capacity (mean 8192, +22 sigma)
#define LCAP 9216           // LDS staging capacity (mean 8192, +11 sigma)
#define HPAD 400            // >= Bsb = ceil(N/256) = 391
#define BINTHREADS 1024
#define ITEMS 8             // edges per thread in k_p1

__global__ void k_init(int* __restrict__ gcur, int Bsb) {
    int i = blockIdx.x * blockDim.x + threadIdx.x;
    if (i < Bsb) gcur[i] = i * SBCAP;
}

// Pass 1: counting scatter into super-bucket regions. Per-block LDS histogram,
// one bulk global claim per super-bucket (~21-int runs at ITEMS=8).
__global__ __launch_bounds__(BINTHREADS) void k_p1(
    const int* __restrict__ src, const int* __restrict__ dst,
    int* __restrict__ gcur, int* __restrict__ pairs, int E, int Bsb)
{
    __shared__ int hist[HPAD];
    const int t = threadIdx.x;
    const int base4 = blockIdx.x * (BINTHREADS * ITEMS / 4);
    for (int i = t; i < HPAD; i += BINTHREADS) hist[i] = 0;
    __syncthreads();

    int4 dd[ITEMS / 4];
    #pragma unroll
    for (int r = 0; r < ITEMS / 4; ++r) {
        const int i4 = base4 + r * BINTHREADS + t;
        const int i = i4 << 2;
        int4 v;
        if (i + 3 < E) v = ((const int4*)dst)[i4];
        else {
            v.x = (i     < E) ? dst[i]     : -1;
            v.y = (i + 1 < E) ? dst[i + 1] : -1;
            v.z = (i + 2 < E) ? dst[i + 2] : -1;
            v.w = (i + 3 < E) ? dst[i + 3] : -1;
        }
        dd[r] = v;
        if (v.x >= 0) atomicAdd(&hist[v.x >> SBSH], 1);
        if (v.y >= 0) atomicAdd(&hist[v.y >> SBSH], 1);
        if (v.z >= 0) atomicAdd(&hist[v.z >> SBSH], 1);
        if (v.w >= 0) atomicAdd(&hist[v.w >> SBSH], 1);
    }
    __syncthreads();
    for (int i = t; i < Bsb; i += BINTHREADS) {
        int c = hist[i];
        hist[i] = c ? atomicAdd(&gcur[i], c) : 0;   // bulk claim -> abs base
    }
    __syncthreads();
    #pragma unroll
    for (int r = 0; r < ITEMS / 4; ++r) {
        const int i4 = base4 + r * BINTHREADS + t;
        const int i = i4 << 2;
        int4 s;
        if (i + 3 < E) s = ((const int4*)src)[i4];
        else {
            s.x = (i     < E) ? src[i]     : 0;
            s.y = (i + 1 < E) ? src[i + 1] : 0;
            s.z = (i + 2 < E) ? src[i + 2] : 0;
            s.w = (i + 3 < E) ? src[i + 3] : 0;
        }
        int4 v = dd[r];
        if (v.x >= 0) { int p = atomicAdd(&hist[v.x >> SBSH], 1); pairs[p] = (s.x << SBSH) | (v.x & 255); }
        if (v.y >= 0) { int p = atomicAdd(&hist[v.y >> SBSH], 1); pairs[p] = (s.y << SBSH) | (v.y & 255); }
        if (v.z >= 0) { int p = atomicAdd(&hist[v.z >> SBSH], 1); pairs[p] = (s.z << SBSH) | (v.z & 255); }
        if (v.w >= 0) { int p = atomicAdd(&hist[v.w >> SBSH], 1); pairs[p] = (s.w << SBSH) | (v.w & 255); }
    }
}

// Pass 2: per-super-bucket counting sort by 8-bit local dst.
// R11: scatter goes to LDS (s2), global write-back is contiguous int4.
__global__ __launch_bounds__(1024) void k_sortsb(
    int* __restrict__ pairs, const int* __restrict__ gcur,
    int* __restrict__ rowp, float* __restrict__ isq, int N)
{
    __shared__ int e[LCAP];              // 36KB staged edges
    __shared__ int s2[LCAP];             // 36KB sorted srcs
    __shared__ int hist[256];
    __shared__ int cur[256];
    __shared__ int wsum[4];
    const int t = threadIdx.x, sb = blockIdx.x;
    const int beg = sb * SBCAP;
    int cnt = gcur[sb] - beg;
    if (cnt > LCAP) cnt = LCAP;          // +11 sigma, statistically never
    if (t < 256) hist[t] = 0;
    __syncthreads();
    const int c4 = cnt >> 2;
    {
        const int4* p4 = (const int4*)(pairs + beg);
        int4* e4 = (int4*)e;
        for (int i = t; i < c4; i += 1024) {
            int4 v = p4[i];
            e4[i] = v;
            atomicAdd(&hist[v.x & 255], 1);
            atomicAdd(&hist[v.y & 255], 1);
            atomicAdd(&hist[v.z & 255], 1);
            atomicAdd(&hist[v.w & 255], 1);
        }
        for (int i = (c4 << 2) + t; i < cnt; i += 1024) {
            int p = pairs[beg + i];
            e[i] = p;
            atomicAdd(&hist[p & 255], 1);
        }
    }
    __syncthreads();
    int c = 0, v = 0;
    if (t < 256) {                       // 4-wave scan of 256 counts
        const int lane = t & 63, w = t >> 6;
        c = hist[t];
        v = c;
        #pragma unroll
        for (int off = 1; off < 64; off <<= 1) {
            int u = __shfl_up(v, off, 64);
            if (lane >= off) v += u;
        }
        if (lane == 63) wsum[w] = v;
    }
    __syncthreads();
    if (t < 256) {
        const int w = t >> 6;
        int add = 0;
        #pragma unroll
        for (int i = 0; i < 3; ++i) if (i < w) add += wsum[i];
        int inc = v + add;               // inclusive prefix
        int exc = inc - c;
        cur[t] = exc;
        rowp[sb * 257 + t] = exc;
        if (t == 255) rowp[sb * 257 + 256] = inc;   // == cnt
        int n = (sb << SBSH) + t;
        if (n < N) isq[n] = rsqrtf((float)(c + 1)); // +1 self loop
    }
    __syncthreads();
    for (int i = t; i < cnt; i += 1024) {
        int p = e[i];
        int pos = atomicAdd(&cur[p & 255], 1);
        s2[pos] = p >> SBSH;             // LDS scatter
    }
    __syncthreads();
    {
        int4* p4 = (int4*)(pairs + beg);
        const int4* s4 = (const int4*)s2;
        for (int i = t; i < c4; i += 1024) p4[i] = s4[i];      // coalesced
        for (int i = (c4 << 2) + t; i < cnt; i += 1024) pairs[beg + i] = s2[i];
    }
}

// hs16[n][f] = half( dot(x[n,:], W1[:,f]) * isq[n] ).
// R11: 2-way K-split by wave. Block = 4 waves, 128 nodes: waves 0,1 do
// k=0..127 for nodes [0..63],[64..127]; waves 2,3 do k=128..255. Half-index
// hu is readfirstlane'd -> W1 addresses wave-uniform -> s_load. Partials
// combined through 8KB LDS (f4-XOR swizzle, <=2-way conflicts).
__global__ __launch_bounds__(256) void k_lin1(
    const float* __restrict__ x, const float* __restrict__ W1,
    const float* __restrict__ isq, __half* __restrict__ hs16, int N)
{
    __shared__ float part[128][16];
    const int t = threadIdx.x;
    const int w = t >> 6, lane = t & 63;
    const int hu = __builtin_amdgcn_readfirstlane(w >> 1);   // uniform half
    const int nl = ((w & 1) << 6) + lane;                    // 0..127
    const int n = blockIdx.x * 128 + nl;
    const int nc = (n < N) ? n : (N - 1);                    // clamped row
    const float4* xr = (const float4*)(x + ((size_t)nc << 8) + (hu << 7));
    float acc[16];
    #pragma unroll
    for (int f = 0; f < 16; ++f) acc[f] = 0.f;
    #pragma unroll 1
    for (int kb = 0; kb < 4; ++kb) {
        float4 xa[8];
        #pragma unroll
        for (int u = 0; u < 8; ++u) xa[u] = xr[(kb << 3) + u];   // 8 in flight
        #pragma unroll
        for (int u = 0; u < 8; ++u) {
            const int k4 = (kb << 3) + u;                        // 0..31
            // W1 block for k = hu*128 + k4*4 .. +3, float4 index:
            const float4* wr = (const float4*)W1 + (hu << 9) + (k4 << 4);
            const float xv[4] = { xa[u].x, xa[u].y, xa[u].z, xa[u].w };
            #pragma unroll
            for (int j = 0; j < 4; ++j) {
                #pragma unroll
                for (int f4 = 0; f4 < 4; ++f4) {
                    const float4 wv = wr[(j << 2) + f4];         // uniform
                    acc[(f4 << 2) + 0] = fmaf(xv[j], wv.x, acc[(f4 << 2) + 0]);
                    acc[(f4 << 2) + 1] = fmaf(xv[j], wv.y, acc[(f4 << 2) + 1]);
                    acc[(f4 << 2) + 2] = fmaf(xv[j], wv.z, acc[(f4 << 2) + 2]);
                    acc[(f4 << 2) + 3] = fmaf(xv[j], wv.w, acc[(f4 << 2) + 3]);
                }
            }
        }
    }
    if (hu == 1) {                       // upper-half waves stage partials
        #pragma unroll
        for (int f4 = 0; f4 < 4; ++f4) {
            const int fs = (f4 ^ (nl & 3)) << 2;
            *(float4*)&part[nl][fs] =
                make_float4(acc[(f4 << 2) + 0], acc[(f4 << 2) + 1],
                            acc[(f4 << 2) + 2], acc[(f4 << 2) + 3]);
        }
    }
    __syncthreads();
    if (hu == 0 && n < N) {
        #pragma unroll
        for (int f4 = 0; f4 < 4; ++f4) {
            const int fs = (f4 ^ (nl & 3)) << 2;
            float4 p = *(const float4*)&part[nl][fs];
            acc[(f4 << 2) + 0] += p.x;
            acc[(f4 << 2) + 1] += p.y;
            acc[(f4 << 2) + 2] += p.z;
            acc[(f4 << 2) + 3] += p.w;
        }
        const float iq = isq[n];
        __half2* o = (__half2*)&hs16[(size_t)n << 4];
        #pragma unroll
        for (int f2 = 0; f2 < 8; ++f2)
            o[f2] = __floats2half2_rn(acc[2 * f2] * iq, acc[2 * f2 + 1] * iq);
    }
}

// Layer-1 aggregation: 4 lanes per node (4 features each, 8B loads), run-scan
// with register accumulation, fused relu/W2/isq epilogue. No atomics.
__global__ __launch_bounds__(256) void k_agg1(
    const int* __restrict__ sorted, const int* __restrict__ rowp,
    const __half* __restrict__ hs16, const float* __restrict__ isq,
    const float* __restrict__ b1, const float* __restrict__ W2,
    float* __restrict__ ts, int N)
{
    const int t = threadIdx.x, g = blockIdx.x;
    const int l = t >> 2, q = t & 3;
    const int n = g * 64 + l;
    if (n >= N) return;
    const int sb = n >> SBSH, L = n & 255;
    const int rbeg = sb * SBCAP + rowp[sb * 257 + L];
    const int rend = sb * SBCAP + rowp[sb * 257 + L + 1];
    const float2* h2 = (const float2*)hs16;
    float a0 = 0.f, a1 = 0.f, a2 = 0.f, a3 = 0.f;
    int j = rbeg;
    for (; j + 2 <= rend; j += 2) {
        int s0 = sorted[j], s1 = sorted[j + 1];
        float2 ra = h2[s0 * 4 + q];
        float2 rb = h2[s1 * 4 + q];
        union { float f; __half2 h; } ca0, ca1, cb0, cb1;
        ca0.f = ra.x; ca1.f = ra.y; cb0.f = rb.x; cb1.f = rb.y;
        float2 fa0 = __half22float2(ca0.h), fa1 = __half22float2(ca1.h);
        float2 fb0 = __half22float2(cb0.h), fb1 = __half22float2(cb1.h);
        a0 += fa0.x + fb0.x; a1 += fa0.y + fb0.y;
        a2 += fa1.x + fb1.x; a3 += fa1.y + fb1.y;
    }
    if (j < rend) {
        int s0 = sorted[j];
        float2 ra = h2[s0 * 4 + q];
        union { float f; __half2 h; } ca0, ca1;
        ca0.f = ra.x; ca1.f = ra.y;
        float2 fa0 = __half22float2(ca0.h), fa1 = __half22float2(ca1.h);
        a0 += fa0.x; a1 += fa0.y; a2 += fa1.x; a3 += fa1.y;
    }
    {   // self loop
        float2 rs = h2[(size_t)n * 4 + q];
        union { float f; __half2 h; } c0, c1;
        c0.f = rs.x; c1.f = rs.y;
        float2 f0 = __half22float2(c0.h), f1 = __half22float2(c1.h);
        a0 += f0.x; a1 += f0.y; a2 += f1.x; a3 += f1.y;
    }
    const float iq = isq[n];
    const int f0i = q * 4;
    float p = fmaxf(a0 * iq + b1[f0i + 0], 0.f) * W2[f0i + 0]
            + fmaxf(a1 * iq + b1[f0i + 1], 0.f) * W2[f0i + 1]
            + fmaxf(a2 * iq + b1[f0i + 2], 0.f) * W2[f0i + 2]
            + fmaxf(a3 * iq + b1[f0i + 3], 0.f) * W2[f0i + 3];
    p += __shfl_xor(p, 1, 4);
    p += __shfl_xor(p, 2, 4);
    if (q == 0) ts[n] = p * iq;
}

// Layer-2: R11: 4 lanes per node striding the run (coalesced sorted reads),
// shfl width-4 reduce. Grid 1563 blocks (was 391 -> wave-starved).
__global__ __launch_bounds__(256) void k_agg2(
    const int* __restrict__ sorted, const int* __restrict__ rowp,
    const float* __restrict__ ts, const float* __restrict__ isq,
    const float* __restrict__ b2, float* __restrict__ out, int N)
{
    const int t = threadIdx.x;
    const int l = t >> 2, q = t & 3;
    const int n = blockIdx.x * 64 + l;
    if (n >= N) return;
    const int sb = n >> SBSH, L = n & 255;
    const int rbeg = sb * SBCAP + rowp[sb * 257 + L];
    const int rend = sb * SBCAP + rowp[sb * 257 + L + 1];
    float acc = 0.f;
    for (int j = rbeg + q; j < rend; j += 4) acc += ts[sorted[j]];
    acc += __shfl_xor(acc, 1, 4);
    acc += __shfl_xor(acc, 2, 4);
    if (q == 0) out[n] = (acc + ts[n]) * isq[n] + b2[0];
}

extern "C" void kernel_launch(void* const* d_in, const int* in_sizes, int n_in,
                              void* d_out, int out_size, void* d_ws, size_t ws_size,
                              hipStream_t stream) {
    const float* x  = (const float*)d_in[0];
    const int*   ei = (const int*)d_in[1];
    const float* W1 = (const float*)d_in[2];
    const float* b1 = (const float*)d_in[3];
    const float* W2 = (const float*)d_in[4];
    const float* b2 = (const float*)d_in[5];
    const int N = in_sizes[0] / 256;
    const int E = in_sizes[1] / 2;
    const int* src = ei;
    const int* dst = ei + E;
    const int Bsb = (N + 255) >> SBSH;   // 391

    char* w = (char*)d_ws;
    float*  isq   = (float*)w;  w += (size_t)N * 4;
    int*    gcur  = (int*)w;    w += HPAD * 4;
    int*    pairs = (int*)w;    w += (size_t)Bsb * SBCAP * 4;   // 16.0 MB
    int*    rowp  = (int*)w;    w += (size_t)Bsb * 257 * 4;     // 402 KB
    __half* hs16  = (__half*)w; w += (size_t)N * 32;            // 3.2 MB
    float*  ts    = (float*)w;  w += (size_t)N * 4;
    float*  out   = (float*)d_out;

    k_init<<<(Bsb + 255) / 256, 256, 0, stream>>>(gcur, Bsb);

    const int nbBin = (E + BINTHREADS * ITEMS - 1) / (BINTHREADS * ITEMS);  // 391
    k_p1<<<nbBin, BINTHREADS, 0, stream>>>(src, dst, gcur, pairs, E, Bsb);

    k_sortsb<<<Bsb, 1024, 0, stream>>>(pairs, gcur, rowp, isq, N);

    k_lin1<<<(N + 127) / 128, 256, 0, stream>>>(x, W1, isq, hs16, N);

    k_agg1<<<(N + 63) / 64, 256, 0, stream>>>(pairs, rowp, hs16, isq, b1, W2, ts, N);
    k_agg2<<<(N + 63) / 64, 256, 0, stream>>>(pairs, rowp, ts, isq, b2, out, N);
}

// Round 4
// 277.138 us; speedup vs baseline: 1.1337x; 1.0125x over previous
//
#include <hip/hip_runtime.h>
#include <hip/hip_fp16.h>

// GCN 2-layer: 256 -> 16 -> 1, N=100000, E=3.2M + self loops.
// R8: two-level radix. k_p1 bins edges by super-bucket (256 nodes, dst>>8);
// k_sortsb counting-sorts each super-bucket (8-bit local key) -> dst-sorted
// src lists + rowp + isq.
//   out[d] = isq[d]*(sum_src ts[src] + ts[d]) + b2,  ts = (h2 @ W2)*isq
//   h2 = relu(isq[d]*(sum_src hs[src] + hs[d]) + b1), hs = (x @ W1)*isq
// R10: k_p1 ITEMS 8 (391 blocks).
// R11: k_lin1 2-wave K-split (s_load W1); sortsb LDS scatter + coalesced
//      write-back; agg2 4 lanes/node.
// R12: (a) gcur padded to 64B/entry — 391 blocks' bulk-claim atomics went to
//      ~25 shared cache lines (~6250 same-line serialized atomics/line);
//      (b) k_agg1 8 lanes/node (4 feature-lanes x 2 run-parity lanes):
//      dependent-gather chain /2, waves/SIMD 6->12; (c) k_agg2 8 lanes/node.

#define SBSH 8              // 256 nodes per super-bucket
#define SBCAP 10240         // global region capacity (mean 8192, +22 sigma)
#define LCAP 9216           // LDS staging capacity (mean 8192, +11 sigma)
#define HPAD 400            // >= Bsb = ceil(N/256) = 391
#define GSTR 16             // gcur stride in ints (64B: one L2 line/entry)
#define BINTHREADS 1024
#define ITEMS 8             // edges per thread in k_p1

__global__ void k_init(int* __restrict__ gcur, int Bsb) {
    int i = blockIdx.x * blockDim.x + threadIdx.x;
    if (i < Bsb) gcur[i * GSTR] = i * SBCAP;
}

// Pass 1: counting scatter into super-bucket regions. Per-block LDS histogram,
// one bulk global claim per super-bucket (~21-int runs at ITEMS=8).
__global__ __launch_bounds__(BINTHREADS) void k_p1(
    const int* __restrict__ src, const int* __restrict__ dst,
    int* __restrict__ gcur, int* __restrict__ pairs, int E, int Bsb)
{
    __shared__ int hist[HPAD];
    const int t = threadIdx.x;
    const int base4 = blockIdx.x * (BINTHREADS * ITEMS / 4);
    for (int i = t; i < HPAD; i += BINTHREADS) hist[i] = 0;
    __syncthreads();

    int4 dd[ITEMS / 4];
    #pragma unroll
    for (int r = 0; r < ITEMS / 4; ++r) {
        const int i4 = base4 + r * BINTHREADS + t;
        const int i = i4 << 2;
        int4 v;
        if (i + 3 < E) v = ((const int4*)dst)[i4];
        else {
            v.x = (i     < E) ? dst[i]     : -1;
            v.y = (i + 1 < E) ? dst[i + 1] : -1;
            v.z = (i + 2 < E) ? dst[i + 2] : -1;
            v.w = (i + 3 < E) ? dst[i + 3] : -1;
        }
        dd[r] = v;
        if (v.x >= 0) atomicAdd(&hist[v.x >> SBSH], 1);
        if (v.y >= 0) atomicAdd(&hist[v.y >> SBSH], 1);
        if (v.z >= 0) atomicAdd(&hist[v.z >> SBSH], 1);
        if (v.w >= 0) atomicAdd(&hist[v.w >> SBSH], 1);
    }
    __syncthreads();
    for (int i = t; i < Bsb; i += BINTHREADS) {
        int c = hist[i];
        hist[i] = c ? atomicAdd(&gcur[i * GSTR], c) : 0;  // bulk claim -> abs base
    }
    __syncthreads();
    #pragma unroll
    for (int r = 0; r < ITEMS / 4; ++r) {
        const int i4 = base4 + r * BINTHREADS + t;
        const int i = i4 << 2;
        int4 s;
        if (i + 3 < E) s = ((const int4*)src)[i4];
        else {
            s.x = (i     < E) ? src[i]     : 0;
            s.y = (i + 1 < E) ? src[i + 1] : 0;
            s.z = (i + 2 < E) ? src[i + 2] : 0;
            s.w = (i + 3 < E) ? src[i + 3] : 0;
        }
        int4 v = dd[r];
        if (v.x >= 0) { int p = atomicAdd(&hist[v.x >> SBSH], 1); pairs[p] = (s.x << SBSH) | (v.x & 255); }
        if (v.y >= 0) { int p = atomicAdd(&hist[v.y >> SBSH], 1); pairs[p] = (s.y << SBSH) | (v.y & 255); }
        if (v.z >= 0) { int p = atomicAdd(&hist[v.z >> SBSH], 1); pairs[p] = (s.z << SBSH) | (v.z & 255); }
        if (v.w >= 0) { int p = atomicAdd(&hist[v.w >> SBSH], 1); pairs[p] = (s.w << SBSH) | (v.w & 255); }
    }
}

// Pass 2: per-super-bucket counting sort by 8-bit local dst.
// Scatter goes to LDS (s2), global write-back is contiguous int4.
__global__ __launch_bounds__(1024) void k_sortsb(
    int* __restrict__ pairs, const int* __restrict__ gcur,
    int* __restrict__ rowp, float* __restrict__ isq, int N)
{
    __shared__ int e[LCAP];              // 36KB staged edges
    __shared__ int s2[LCAP];             // 36KB sorted srcs
    __shared__ int hist[256];
    __shared__ int cur[256];
    __shared__ int wsum[4];
    const int t = threadIdx.x, sb = blockIdx.x;
    const int beg = sb * SBCAP;
    int cnt = gcur[sb * GSTR] - beg;
    if (cnt > LCAP) cnt = LCAP;          // +11 sigma, statistically never
    if (t < 256) hist[t] = 0;
    __syncthreads();
    const int c4 = cnt >> 2;
    {
        const int4* p4 = (const int4*)(pairs + beg);
        int4* e4 = (int4*)e;
        for (int i = t; i < c4; i += 1024) {
            int4 v = p4[i];
            e4[i] = v;
            atomicAdd(&hist[v.x & 255], 1);
            atomicAdd(&hist[v.y & 255], 1);
            atomicAdd(&hist[v.z & 255], 1);
            atomicAdd(&hist[v.w & 255], 1);
        }
        for (int i = (c4 << 2) + t; i < cnt; i += 1024) {
            int p = pairs[beg + i];
            e[i] = p;
            atomicAdd(&hist[p & 255], 1);
        }
    }
    __syncthreads();
    int c = 0, v = 0;
    if (t < 256) {                       // 4-wave scan of 256 counts
        const int lane = t & 63, w = t >> 6;
        c = hist[t];
        v = c;
        #pragma unroll
        for (int off = 1; off < 64; off <<= 1) {
            int u = __shfl_up(v, off, 64);
            if (lane >= off) v += u;
        }
        if (lane == 63) wsum[w] = v;
    }
    __syncthreads();
    if (t < 256) {
        const int w = t >> 6;
        int add = 0;
        #pragma unroll
        for (int i = 0; i < 3; ++i) if (i < w) add += wsum[i];
        int inc = v + add;               // inclusive prefix
        int exc = inc - c;
        cur[t] = exc;
        rowp[sb * 257 + t] = exc;
        if (t == 255) rowp[sb * 257 + 256] = inc;   // == cnt
        int n = (sb << SBSH) + t;
        if (n < N) isq[n] = rsqrtf((float)(c + 1)); // +1 self loop
    }
    __syncthreads();
    for (int i = t; i < cnt; i += 1024) {
        int p = e[i];
        int pos = atomicAdd(&cur[p & 255], 1);
        s2[pos] = p >> SBSH;             // LDS scatter
    }
    __syncthreads();
    {
        int4* p4 = (int4*)(pairs + beg);
        const int4* s4 = (const int4*)s2;
        for (int i = t; i < c4; i += 1024) p4[i] = s4[i];      // coalesced
        for (int i = (c4 << 2) + t; i < cnt; i += 1024) pairs[beg + i] = s2[i];
    }
}

// hs16[n][f] = half( dot(x[n,:], W1[:,f]) * isq[n] ).
// 2-way K-split by wave; readfirstlane keeps W1 index wave-uniform -> s_load.
__global__ __launch_bounds__(256) void k_lin1(
    const float* __restrict__ x, const float* __restrict__ W1,
    const float* __restrict__ isq, __half* __restrict__ hs16, int N)
{
    __shared__ float part[128][16];
    const int t = threadIdx.x;
    const int w = t >> 6, lane = t & 63;
    const int hu = __builtin_amdgcn_readfirstlane(w >> 1);   // uniform half
    const int nl = ((w & 1) << 6) + lane;                    // 0..127
    const int n = blockIdx.x * 128 + nl;
    const int nc = (n < N) ? n : (N - 1);                    // clamped row
    const float4* xr = (const float4*)(x + ((size_t)nc << 8) + (hu << 7));
    float acc[16];
    #pragma unroll
    for (int f = 0; f < 16; ++f) acc[f] = 0.f;
    #pragma unroll 1
    for (int kb = 0; kb < 4; ++kb) {
        float4 xa[8];
        #pragma unroll
        for (int u = 0; u < 8; ++u) xa[u] = xr[(kb << 3) + u];   // 8 in flight
        #pragma unroll
        for (int u = 0; u < 8; ++u) {
            const int k4 = (kb << 3) + u;                        // 0..31
            const float4* wr = (const float4*)W1 + (hu << 9) + (k4 << 4);
            const float xv[4] = { xa[u].x, xa[u].y, xa[u].z, xa[u].w };
            #pragma unroll
            for (int j = 0; j < 4; ++j) {
                #pragma unroll
                for (int f4 = 0; f4 < 4; ++f4) {
                    const float4 wv = wr[(j << 2) + f4];         // uniform
                    acc[(f4 << 2) + 0] = fmaf(xv[j], wv.x, acc[(f4 << 2) + 0]);
                    acc[(f4 << 2) + 1] = fmaf(xv[j], wv.y, acc[(f4 << 2) + 1]);
                    acc[(f4 << 2) + 2] = fmaf(xv[j], wv.z, acc[(f4 << 2) + 2]);
                    acc[(f4 << 2) + 3] = fmaf(xv[j], wv.w, acc[(f4 << 2) + 3]);
                }
            }
        }
    }
    if (hu == 1) {                       // upper-half waves stage partials
        #pragma unroll
        for (int f4 = 0; f4 < 4; ++f4) {
            const int fs = (f4 ^ (nl & 3)) << 2;
            *(float4*)&part[nl][fs] =
                make_float4(acc[(f4 << 2) + 0], acc[(f4 << 2) + 1],
                            acc[(f4 << 2) + 2], acc[(f4 << 2) + 3]);
        }
    }
    __syncthreads();
    if (hu == 0 && n < N) {
        #pragma unroll
        for (int f4 = 0; f4 < 4; ++f4) {
            const int fs = (f4 ^ (nl & 3)) << 2;
            float4 p = *(const float4*)&part[nl][fs];
            acc[(f4 << 2) + 0] += p.x;
            acc[(f4 << 2) + 1] += p.y;
            acc[(f4 << 2) + 2] += p.z;
            acc[(f4 << 2) + 3] += p.w;
        }
        const float iq = isq[n];
        __half2* o = (__half2*)&hs16[(size_t)n << 4];
        #pragma unroll
        for (int f2 = 0; f2 < 8; ++f2)
            o[f2] = __floats2half2_rn(acc[2 * f2] * iq, acc[2 * f2 + 1] * iq);
    }
}

// Layer-1 aggregation. R12: 8 lanes/node = 4 feature-lanes (q, 4 features
// each, 8B loads) x 2 run-parity lanes (p). Parity halves the dependent
// gather chain; shfl_xor(4) combines; self-loop added post-combine (all
// lanes redundantly compute the final value, lane t&7==0 writes).
__global__ __launch_bounds__(256) void k_agg1(
    const int* __restrict__ sorted, const int* __restrict__ rowp,
    const __half* __restrict__ hs16, const float* __restrict__ isq,
    const float* __restrict__ b1, const float* __restrict__ W2,
    float* __restrict__ ts, int N)
{
    const int t = threadIdx.x, g = blockIdx.x;
    const int l = t >> 3, q = t & 3, p = (t >> 2) & 1;
    const int n = g * 32 + l;
    if (n >= N) return;
    const int sb = n >> SBSH, L = n & 255;
    const int rbeg = sb * SBCAP + rowp[sb * 257 + L];
    const int rend = sb * SBCAP + rowp[sb * 257 + L + 1];
    const float2* h2 = (const float2*)hs16;
    float a0 = 0.f, a1 = 0.f, a2 = 0.f, a3 = 0.f;
    for (int j = rbeg + p; j < rend; j += 2) {
        int s0 = sorted[j];
        float2 ra = h2[s0 * 4 + q];
        union { float f; __half2 h; } ca0, ca1;
        ca0.f = ra.x; ca1.f = ra.y;
        float2 fa0 = __half22float2(ca0.h), fa1 = __half22float2(ca1.h);
        a0 += fa0.x; a1 += fa0.y; a2 += fa1.x; a3 += fa1.y;
    }
    // combine the two parity halves (lanes t and t^4)
    a0 += __shfl_xor(a0, 4);
    a1 += __shfl_xor(a1, 4);
    a2 += __shfl_xor(a2, 4);
    a3 += __shfl_xor(a3, 4);
    {   // self loop (post-combine: both parity lanes hold the full sum)
        float2 rs = h2[(size_t)n * 4 + q];
        union { float f; __half2 h; } c0, c1;
        c0.f = rs.x; c1.f = rs.y;
        float2 f0 = __half22float2(c0.h), f1 = __half22float2(c1.h);
        a0 += f0.x; a1 += f0.y; a2 += f1.x; a3 += f1.y;
    }
    const float iq = isq[n];
    const int f0i = q * 4;
    float pr = fmaxf(a0 * iq + b1[f0i + 0], 0.f) * W2[f0i + 0]
             + fmaxf(a1 * iq + b1[f0i + 1], 0.f) * W2[f0i + 1]
             + fmaxf(a2 * iq + b1[f0i + 2], 0.f) * W2[f0i + 2]
             + fmaxf(a3 * iq + b1[f0i + 3], 0.f) * W2[f0i + 3];
    pr += __shfl_xor(pr, 1);
    pr += __shfl_xor(pr, 2);
    if ((t & 7) == 0) ts[n] = pr * iq;
}

// Layer-2. R12: 8 lanes/node striding the run (chain /2, waves/SIMD 12).
__global__ __launch_bounds__(256) void k_agg2(
    const int* __restrict__ sorted, const int* __restrict__ rowp,
    const float* __restrict__ ts, const float* __restrict__ isq,
    const float* __restrict__ b2, float* __restrict__ out, int N)
{
    const int t = threadIdx.x;
    const int l = t >> 3, q = t & 7;
    const int n = blockIdx.x * 32 + l;
    if (n >= N) return;
    const int sb = n >> SBSH, L = n & 255;
    const int rbeg = sb * SBCAP + rowp[sb * 257 + L];
    const int rend = sb * SBCAP + rowp[sb * 257 + L + 1];
    float acc = 0.f;
    for (int j = rbeg + q; j < rend; j += 8) acc += ts[sorted[j]];
    acc += __shfl_xor(acc, 1);
    acc += __shfl_xor(acc, 2);
    acc += __shfl_xor(acc, 4);
    if (q == 0) out[n] = (acc + ts[n]) * isq[n] + b2[0];
}

extern "C" void kernel_launch(void* const* d_in, const int* in_sizes, int n_in,
                              void* d_out, int out_size, void* d_ws, size_t ws_size,
                              hipStream_t stream) {
    const float* x  = (const float*)d_in[0];
    const int*   ei = (const int*)d_in[1];
    const float* W1 = (const float*)d_in[2];
    const float* b1 = (const float*)d_in[3];
    const float* W2 = (const float*)d_in[4];
    const float* b2 = (const float*)d_in[5];
    const int N = in_sizes[0] / 256;
    const int E = in_sizes[1] / 2;
    const int* src = ei;
    const int* dst = ei + E;
    const int Bsb = (N + 255) >> SBSH;   // 391

    char* w = (char*)d_ws;
    float*  isq   = (float*)w;  w += (size_t)N * 4;
    int*    gcur  = (int*)w;    w += (size_t)HPAD * GSTR * 4;   // 25.6 KB padded
    int*    pairs = (int*)w;    w += (size_t)Bsb * SBCAP * 4;   // 16.0 MB
    int*    rowp  = (int*)w;    w += (size_t)Bsb * 257 * 4;     // 402 KB
    __half* hs16  = (__half*)w; w += (size_t)N * 32;            // 3.2 MB
    float*  ts    = (float*)w;  w += (size_t)N * 4;
    float*  out   = (float*)d_out;

    k_init<<<(Bsb + 255) / 256, 256, 0, stream>>>(gcur, Bsb);

    const int nbBin = (E + BINTHREADS * ITEMS - 1) / (BINTHREADS * ITEMS);  // 391
    k_p1<<<nbBin, BINTHREADS, 0, stream>>>(src, dst, gcur, pairs, E, Bsb);

    k_sortsb<<<Bsb, 1024, 0, stream>>>(pairs, gcur, rowp, isq, N);

    k_lin1<<<(N + 127) / 128, 256, 0, stream>>>(x, W1, isq, hs16, N);

    k_agg1<<<(N + 31) / 32, 256, 0, stream>>>(pairs, rowp, hs16, isq, b1, W2, ts, N);
    k_agg2<<<(N + 31) / 32, 256, 0, stream>>>(pairs, rowp, ts, isq, b2, out, N);
}